// Round 5
// baseline (552.497 us; speedup 1.0000x reference)
//
#include <hip/hip_runtime.h>
#include <cstdint>

#define HIDDEN 128

using frag_t  = __attribute__((ext_vector_type(8))) short;   // 8 bf16 (4 VGPRs)
using f32x4_t = __attribute__((ext_vector_type(4))) float;   // MFMA accumulator

__device__ __forceinline__ float bf2f(unsigned short u) {
    union { unsigned int i; float f; } c;
    c.i = ((unsigned int)u) << 16;
    return c.f;
}
__device__ __forceinline__ unsigned short f2bf(float f) {
    unsigned int u = __float_as_uint(f);
    unsigned int r = (u + 0x7fffu + ((u >> 16) & 1u)) >> 16;   // RNE
    return (unsigned short)r;
}

// ---------------- CSR build (edge_index arrives as int32 from harness) ----------------

__global__ void k_hist(const int* __restrict__ ei, int E, int* __restrict__ deg) {
    int i = blockIdx.x * blockDim.x + threadIdx.x;
    int stride = gridDim.x * blockDim.x;
    for (int e = i; e < E; e += stride) atomicAdd(&deg[ei[E + e]], 1);
}

__global__ void k_scan1(const int* __restrict__ deg, int* __restrict__ rowp,
                        int* __restrict__ bsums, int n) {
    __shared__ int sh[1024];
    int t = threadIdx.x;
    int base = blockIdx.x * 1024;
    int v = (base + t < n) ? deg[base + t] : 0;
    sh[t] = v;
    __syncthreads();
    for (int off = 1; off < 1024; off <<= 1) {
        int x = sh[t];
        int y = (t >= off) ? sh[t - off] : 0;
        __syncthreads();
        sh[t] = x + y;
        __syncthreads();
    }
    if (base + t < n) rowp[base + t + 1] = sh[t];
    if (t == 1023) bsums[blockIdx.x] = sh[1023];
}

__global__ void k_scan2(int* __restrict__ bsums, int nb) {
    if (threadIdx.x == 0 && blockIdx.x == 0) {
        int run = 0;
        for (int b = 0; b < nb; ++b) { int v = bsums[b]; bsums[b] = run; run += v; }
    }
}

// also fills fillpos with the exclusive prefix (rowp[i]) so k_copy is not needed
__global__ void k_scan3(int* __restrict__ rowp, const int* __restrict__ boffs,
                        int* __restrict__ fillp, int n) {
    int t = threadIdx.x;
    int b = blockIdx.x;
    int base = b * 1024;
    if (base + t < n) {
        int v = rowp[base + t + 1] + boffs[b];
        rowp[base + t + 1] = v;
        if (base + t + 1 < n) fillp[base + t + 1] = v;
    }
    if (b == 0 && t == 0) { rowp[0] = 0; fillp[0] = 0; }
}

__global__ void k_fill(const int* __restrict__ ei, int E,
                       int* __restrict__ fillpos, int* __restrict__ colx) {
    int i = blockIdx.x * blockDim.x + threadIdx.x;
    int stride = gridDim.x * blockDim.x;
    for (int e = i; e < E; e += stride) {
        int s = ei[e];
        int d = ei[E + e];
        int p = atomicAdd(&fillpos[d], 1);
        colx[p] = s;
    }
}

// ---------------- weight prep: transpose + split fp32 -> bf16 hi/lo, layout Wt[n][k] ----------------
// W_in [64][128] -> WtI [128][64]; W_self/W_nbr [3][128][128] -> [3][128][128] transposed.

__global__ void k_prep_w(const float* __restrict__ W_in,
                         const float* __restrict__ W_self,
                         const float* __restrict__ W_nbr,
                         unsigned short* __restrict__ WtI_hi, unsigned short* __restrict__ WtI_lo,
                         unsigned short* __restrict__ WtS_hi, unsigned short* __restrict__ WtS_lo,
                         unsigned short* __restrict__ WtN_hi, unsigned short* __restrict__ WtN_lo,
                         int L) {
    int idx = blockIdx.x * blockDim.x + threadIdx.x;
    int nIn = 64 * 128;
    int nSq = L * 128 * 128;
    float v; unsigned short* phi; unsigned short* plo; int o;
    if (idx < nIn) {
        int n = idx / 64, k = idx % 64;
        v = W_in[k * 128 + n]; phi = WtI_hi; plo = WtI_lo; o = n * 64 + k;
    } else if (idx < nIn + nSq) {
        int t = idx - nIn;
        int l = t / (128 * 128), r = t % (128 * 128);
        int n = r / 128, k = r % 128;
        v = W_self[l * 128 * 128 + k * 128 + n]; phi = WtS_hi; plo = WtS_lo;
        o = l * 128 * 128 + n * 128 + k;
    } else if (idx < nIn + 2 * nSq) {
        int t = idx - nIn - nSq;
        int l = t / (128 * 128), r = t % (128 * 128);
        int n = r / 128, k = r % 128;
        v = W_nbr[l * 128 * 128 + k * 128 + n]; phi = WtN_hi; plo = WtN_lo;
        o = l * 128 * 128 + n * 128 + k;
    } else return;
    unsigned short hi = f2bf(v);
    phi[o] = hi;
    plo[o] = f2bf(v - bf2f(hi));
}

// x [N][64] fp32 -> bf16 hi/lo (same layout)
__global__ void k_prep_x(const float* __restrict__ x,
                         unsigned short* __restrict__ xhi, unsigned short* __restrict__ xlo,
                         int total) {
    int i = blockIdx.x * blockDim.x + threadIdx.x;
    int stride = gridDim.x * blockDim.x;
    for (; i < total; i += stride) {
        float v = x[i];
        unsigned short hi = f2bf(v);
        xhi[i] = hi;
        xlo[i] = f2bf(v - bf2f(hi));
    }
}

// ---------------- aggregation: Sb = bf16_hi/lo of mean over CSR row of hb_hi rows ----------------

__global__ void k_agg(const ushort4* __restrict__ hb4, const int* __restrict__ rowp,
                      const int* __restrict__ colx,
                      ushort4* __restrict__ Shi4, ushort4* __restrict__ Slo4, int n) {
    int g = (blockIdx.x * blockDim.x + threadIdx.x) >> 5;   // 32 lanes/node, lane = 4 cols
    int lane = threadIdx.x & 31;
    if (g >= n) return;
    int beg = rowp[g];
    int end = rowp[g + 1];
    float4 a0 = make_float4(0.f, 0.f, 0.f, 0.f);
    float4 a1 = a0, a2 = a0, a3 = a0;
    int e = beg;
    for (; e + 3 < end; e += 4) {
        int s0 = colx[e], s1 = colx[e + 1], s2 = colx[e + 2], s3 = colx[e + 3];
        ushort4 v0 = hb4[(size_t)s0 * 32 + lane];
        ushort4 v1 = hb4[(size_t)s1 * 32 + lane];
        ushort4 v2 = hb4[(size_t)s2 * 32 + lane];
        ushort4 v3 = hb4[(size_t)s3 * 32 + lane];
        a0.x += bf2f(v0.x); a0.y += bf2f(v0.y); a0.z += bf2f(v0.z); a0.w += bf2f(v0.w);
        a1.x += bf2f(v1.x); a1.y += bf2f(v1.y); a1.z += bf2f(v1.z); a1.w += bf2f(v1.w);
        a2.x += bf2f(v2.x); a2.y += bf2f(v2.y); a2.z += bf2f(v2.z); a2.w += bf2f(v2.w);
        a3.x += bf2f(v3.x); a3.y += bf2f(v3.y); a3.z += bf2f(v3.z); a3.w += bf2f(v3.w);
    }
    for (; e < end; ++e) {
        int s = colx[e];
        ushort4 v = hb4[(size_t)s * 32 + lane];
        a0.x += bf2f(v.x); a0.y += bf2f(v.y); a0.z += bf2f(v.z); a0.w += bf2f(v.w);
    }
    float acc[4];
    acc[0] = (a0.x + a1.x) + (a2.x + a3.x);
    acc[1] = (a0.y + a1.y) + (a2.y + a3.y);
    acc[2] = (a0.z + a1.z) + (a2.z + a3.z);
    acc[3] = (a0.w + a1.w) + (a2.w + a3.w);
    int deg = end - beg;
    float inv = 1.0f / (float)(deg > 1 ? deg : 1);
    ushort4 ohi, olo;
    unsigned short* ph = &ohi.x;
    unsigned short* pl = &olo.x;
#pragma unroll
    for (int c = 0; c < 4; ++c) {
        float v = acc[c] * inv;
        unsigned short hi = f2bf(v);
        ph[c] = hi;
        pl[c] = f2bf(v - bf2f(hi));
    }
    Shi4[(size_t)g * 32 + lane] = ohi;
    Slo4[(size_t)g * 32 + lane] = olo;
}

// ---------------- MFMA GEMM: C = act(A1@W1 + A2@W2 + bias), N=128, no LDS, no barriers ----------
// A row-major bf16 hi/lo [M][K]; W pre-transposed bf16 hi/lo Wt[n][K].
// Per block: 4 waves, block tile 64 rows x 128 cols; wave w owns rows w*16..+15, 8 n-tiles.
// hi/lo split: acc += Ahi*Whi + Alo*Whi + Ahi*Wlo  (fp32-equivalent precision).

template <int K1, int K2>
__global__ __launch_bounds__(256) void k_gemm_mfma(
    const unsigned short* __restrict__ A1h, const unsigned short* __restrict__ A1l,
    const unsigned short* __restrict__ A2h, const unsigned short* __restrict__ A2l,
    const unsigned short* __restrict__ B1h, const unsigned short* __restrict__ B1l,
    const unsigned short* __restrict__ B2h, const unsigned short* __restrict__ B2l,
    const float* __restrict__ bias, float* __restrict__ C,
    unsigned short* __restrict__ Hhi, unsigned short* __restrict__ Hlo,
    int M, int do_elu)
{
    int lane = threadIdx.x & 63;
    int w    = threadIdx.x >> 6;        // wave 0..3
    int m16  = lane & 15;
    int quad = lane >> 4;               // 0..3
    int kq   = quad * 8;
    int row0 = blockIdx.x * 64;
    int gr   = row0 + w * 16 + m16;     // A-fragment row for this lane

    f32x4_t acc[8];
#pragma unroll
    for (int t = 0; t < 8; ++t) acc[t] = (f32x4_t){0.f, 0.f, 0.f, 0.f};

#pragma unroll
    for (int part = 0; part < 2; ++part) {
        const unsigned short* Ah = part ? A2h : A1h;
        const unsigned short* Al = part ? A2l : A1l;
        const unsigned short* Bh = part ? B2h : B1h;
        const unsigned short* Bl = part ? B2l : B1l;
        const int K = part ? K2 : K1;
        if (K == 0) continue;

        for (int k0 = 0; k0 < K; k0 += 32) {
            frag_t ah = {}, al = {};
            if (gr < M) {
                ah = *(const frag_t*)&Ah[(size_t)gr * K + k0 + kq];
                al = *(const frag_t*)&Al[(size_t)gr * K + k0 + kq];
            }
#pragma unroll
            for (int t = 0; t < 8; ++t) {
                size_t bo = (size_t)(t * 16 + m16) * K + k0 + kq;
                frag_t bh = *(const frag_t*)&Bh[bo];
                frag_t bl = *(const frag_t*)&Bl[bo];
                acc[t] = __builtin_amdgcn_mfma_f32_16x16x32_bf16(ah, bh, acc[t], 0, 0, 0);
                acc[t] = __builtin_amdgcn_mfma_f32_16x16x32_bf16(al, bh, acc[t], 0, 0, 0);
                acc[t] = __builtin_amdgcn_mfma_f32_16x16x32_bf16(ah, bl, acc[t], 0, 0, 0);
            }
        }
    }

    // epilogue: C/D layout col=lane&15, row=quad*4+reg
    int r0 = row0 + w * 16 + quad * 4;
#pragma unroll
    for (int t = 0; t < 8; ++t) {
        int col = t * 16 + m16;
        float bv = bias[col];
#pragma unroll
        for (int r = 0; r < 4; ++r) {
            int row = r0 + r;
            if (row < M) {
                float v = acc[t][r] + bv;
                if (do_elu) v = (v > 0.f) ? v : expm1f(v);
                if (C) C[(size_t)row * HIDDEN + col] = v;
                if (Hhi) {
                    unsigned short hi = f2bf(v);
                    Hhi[(size_t)row * HIDDEN + col] = hi;
                    Hlo[(size_t)row * HIDDEN + col] = f2bf(v - bf2f(hi));
                }
            }
        }
    }
}

// ---------------- launch ----------------

extern "C" void kernel_launch(void* const* d_in, const int* in_sizes, int n_in,
                              void* d_out, int out_size, void* d_ws, size_t ws_size,
                              hipStream_t stream) {
    const float* x        = (const float*)d_in[0];
    const int* ei         = (const int*)d_in[1];
    const float* W_in     = (const float*)d_in[2];
    const float* b_in     = (const float*)d_in[3];
    const float* W_self   = (const float*)d_in[4];
    const float* b_self   = (const float*)d_in[5];
    const float* W_nbr    = (const float*)d_in[6];
    float* out = (float*)d_out;

    const int IN_FEAT = 64;
    int N = in_sizes[0] / IN_FEAT;           // 50000
    int E = in_sizes[1] / 2;                 // 800000
    int L = in_sizes[4] / (HIDDEN * HIDDEN); // 3

    char* ws = (char*)d_ws;
    size_t off = 0;
    auto alloc = [&](size_t bytes) -> void* {
        void* p = ws + off;
        off = (off + bytes + 255) & ~(size_t)255;
        return p;
    };

    typedef unsigned short u16;
    u16* hb_hi = (u16*)alloc((size_t)N * HIDDEN * 2);    // 12.8 MB
    u16* hb_lo = (u16*)alloc((size_t)N * HIDDEN * 2);
    // xb region reused as Sb_hi after the input projection consumes it
    u16* xb_hi = (u16*)alloc((size_t)N * IN_FEAT * 2);   // 6.4 MB
    u16* xb_lo = (u16*)alloc((size_t)N * IN_FEAT * 2);   // 6.4 MB
    u16* Sb_hi = xb_hi;                                  // alias (12.8 MB total)
    u16* Sb_lo = (u16*)alloc((size_t)N * HIDDEN * 2);
    u16* WtI_hi = (u16*)alloc(128 * 64 * 2);
    u16* WtI_lo = (u16*)alloc(128 * 64 * 2);
    u16* WtS_hi = (u16*)alloc((size_t)L * 128 * 128 * 2);
    u16* WtS_lo = (u16*)alloc((size_t)L * 128 * 128 * 2);
    u16* WtN_hi = (u16*)alloc((size_t)L * 128 * 128 * 2);
    u16* WtN_lo = (u16*)alloc((size_t)L * 128 * 128 * 2);
    int* deg   = (int*)alloc((size_t)N * sizeof(int));
    int* rowp  = (int*)alloc((size_t)(N + 1) * sizeof(int));
    int* fillp = (int*)alloc((size_t)N * sizeof(int));
    int* colx  = (int*)alloc((size_t)E * sizeof(int));
    int* bsums = (int*)alloc(256 * sizeof(int));

    // CSR build (graph identical across layers)
    hipMemsetAsync(deg, 0, (size_t)N * sizeof(int), stream);
    k_hist<<<512, 256, 0, stream>>>(ei, E, deg);
    int nb = (N + 1023) / 1024;
    k_scan1<<<nb, 1024, 0, stream>>>(deg, rowp, bsums, N);
    k_scan2<<<1, 64, 0, stream>>>(bsums, nb);
    k_scan3<<<nb, 1024, 0, stream>>>(rowp, bsums, fillp, N);
    k_fill<<<1024, 256, 0, stream>>>(ei, E, fillp, colx);

    // prep: weights (transpose+split) and x (split)
    int wtot = 64 * 128 + 2 * L * 128 * 128;
    k_prep_w<<<(wtot + 255) / 256, 256, 0, stream>>>(W_in, W_self, W_nbr,
                                                     WtI_hi, WtI_lo, WtS_hi, WtS_lo,
                                                     WtN_hi, WtN_lo, L);
    k_prep_x<<<1024, 256, 0, stream>>>(x, xb_hi, xb_lo, N * IN_FEAT);

    int gblocks = (N + 63) / 64;

    // input projection: hb = bf16(x @ W_in + b_in)  (no activation, no fp32 C)
    k_gemm_mfma<64, 0><<<gblocks, 256, 0, stream>>>(
        xb_hi, xb_lo, nullptr, nullptr,
        WtI_hi, WtI_lo, nullptr, nullptr,
        b_in, nullptr, hb_hi, hb_lo, N, 0);

    for (int l = 0; l < L; ++l) {
        k_agg<<<(N + 7) / 8, 256, 0, stream>>>((const ushort4*)hb_hi, rowp, colx,
                                               (ushort4*)Sb_hi, (ushort4*)Sb_lo, N);
        const u16* Wsh = WtS_hi + (size_t)l * 128 * 128;
        const u16* Wsl = WtS_lo + (size_t)l * 128 * 128;
        const u16* Wnh = WtN_hi + (size_t)l * 128 * 128;
        const u16* Wnl = WtN_lo + (size_t)l * 128 * 128;
        const float* bs = b_self + (size_t)l * HIDDEN;
        bool last = (l == L - 1);
        // each wave reads/writes only its own 16 rows of hb -> in-place safe
        k_gemm_mfma<128, 128><<<gblocks, 256, 0, stream>>>(
            hb_hi, hb_lo, Sb_hi, Sb_lo,
            Wsh, Wsl, Wnh, Wnl,
            bs, last ? out : nullptr,
            last ? nullptr : hb_hi, last ? nullptr : hb_lo, N, 1);
    }
}

// Round 6
// 469.755 us; speedup vs baseline: 1.1761x; 1.1761x over previous
//
#include <hip/hip_runtime.h>
#include <cstdint>

#define HIDDEN 128

typedef unsigned short u16;
using frag_t  = __attribute__((ext_vector_type(8))) short;   // 8 bf16 (4 VGPRs)
using f32x4_t = __attribute__((ext_vector_type(4))) float;   // MFMA accumulator

__device__ __forceinline__ float bf2f(u16 u) {
    union { unsigned int i; float f; } c;
    c.i = ((unsigned int)u) << 16;
    return c.f;
}
__device__ __forceinline__ u16 f2bf(float f) {
    unsigned int u = __float_as_uint(f);
    unsigned int r = (u + 0x7fffu + ((u >> 16) & 1u)) >> 16;   // RNE
    return (u16)r;
}

// ---------------- CSR build (edge_index arrives as int32 from harness) ----------------

__global__ void k_hist(const int* __restrict__ ei, int E, int* __restrict__ deg) {
    int i = blockIdx.x * blockDim.x + threadIdx.x;
    int stride = gridDim.x * blockDim.x;
    for (int e = i; e < E; e += stride) atomicAdd(&deg[ei[E + e]], 1);
}

__global__ void k_scan1(const int* __restrict__ deg, int* __restrict__ rowp,
                        int* __restrict__ bsums, int n) {
    __shared__ int sh[1024];
    int t = threadIdx.x;
    int base = blockIdx.x * 1024;
    int v = (base + t < n) ? deg[base + t] : 0;
    sh[t] = v;
    __syncthreads();
    for (int off = 1; off < 1024; off <<= 1) {
        int x = sh[t];
        int y = (t >= off) ? sh[t - off] : 0;
        __syncthreads();
        sh[t] = x + y;
        __syncthreads();
    }
    if (base + t < n) rowp[base + t + 1] = sh[t];
    if (t == 1023) bsums[blockIdx.x] = sh[1023];
}

__global__ void k_scan2(int* __restrict__ bsums, int nb) {
    if (threadIdx.x == 0 && blockIdx.x == 0) {
        int run = 0;
        for (int b = 0; b < nb; ++b) { int v = bsums[b]; bsums[b] = run; run += v; }
    }
}

__global__ void k_scan3(int* __restrict__ rowp, const int* __restrict__ boffs,
                        int* __restrict__ fillp, int n) {
    int t = threadIdx.x;
    int b = blockIdx.x;
    int base = b * 1024;
    if (base + t < n) {
        int v = rowp[base + t + 1] + boffs[b];
        rowp[base + t + 1] = v;
        if (base + t + 1 < n) fillp[base + t + 1] = v;
    }
    if (b == 0 && t == 0) { rowp[0] = 0; fillp[0] = 0; }
}

__global__ void k_fill(const int* __restrict__ ei, int E,
                       int* __restrict__ fillpos, int* __restrict__ colx) {
    int i = blockIdx.x * blockDim.x + threadIdx.x;
    int stride = gridDim.x * blockDim.x;
    for (int e = i; e < E; e += stride) {
        int s = ei[e];
        int d = ei[E + e];
        int p = atomicAdd(&fillpos[d], 1);
        colx[p] = s;
    }
}

// ---------------- weight prep: transpose + split fp32 -> bf16 hi/lo, layout Wt[n][k] ----------------

__global__ void k_prep_w(const float* __restrict__ W_in,
                         const float* __restrict__ W_self,
                         const float* __restrict__ W_nbr,
                         u16* __restrict__ WtI_hi, u16* __restrict__ WtI_lo,
                         u16* __restrict__ WtS_hi, u16* __restrict__ WtS_lo,
                         u16* __restrict__ WtN_hi, u16* __restrict__ WtN_lo,
                         int L) {
    int idx = blockIdx.x * blockDim.x + threadIdx.x;
    int nIn = 64 * 128;
    int nSq = L * 128 * 128;
    float v; u16* phi; u16* plo; int o;
    if (idx < nIn) {
        int n = idx / 64, k = idx % 64;
        v = W_in[k * 128 + n]; phi = WtI_hi; plo = WtI_lo; o = n * 64 + k;
    } else if (idx < nIn + nSq) {
        int t = idx - nIn;
        int l = t / (128 * 128), r = t % (128 * 128);
        int n = r / 128, k = r % 128;
        v = W_self[l * 128 * 128 + k * 128 + n]; phi = WtS_hi; plo = WtS_lo;
        o = l * 128 * 128 + n * 128 + k;
    } else if (idx < nIn + 2 * nSq) {
        int t = idx - nIn - nSq;
        int l = t / (128 * 128), r = t % (128 * 128);
        int n = r / 128, k = r % 128;
        v = W_nbr[l * 128 * 128 + k * 128 + n]; phi = WtN_hi; plo = WtN_lo;
        o = l * 128 * 128 + n * 128 + k;
    } else return;
    u16 hi = f2bf(v);
    phi[o] = hi;
    plo[o] = f2bf(v - bf2f(hi));
}

__global__ void k_prep_x(const float* __restrict__ x,
                         u16* __restrict__ xhi, u16* __restrict__ xlo, int total) {
    int i = blockIdx.x * blockDim.x + threadIdx.x;
    int stride = gridDim.x * blockDim.x;
    for (; i < total; i += stride) {
        float v = x[i];
        u16 hi = f2bf(v);
        xhi[i] = hi;
        xlo[i] = f2bf(v - bf2f(hi));
    }
}

// ---------------- aggregation: Sb = bf16_hi/lo of mean over CSR row of hb_hi rows ----------------

__global__ void k_agg(const ushort4* __restrict__ hb4, const int* __restrict__ rowp,
                      const int* __restrict__ colx,
                      ushort4* __restrict__ Shi4, ushort4* __restrict__ Slo4, int n) {
    int g = (blockIdx.x * blockDim.x + threadIdx.x) >> 5;   // 32 lanes/node, lane = 4 cols
    int lane = threadIdx.x & 31;
    if (g >= n) return;
    int beg = rowp[g];
    int end = rowp[g + 1];
    float4 a0 = make_float4(0.f, 0.f, 0.f, 0.f);
    float4 a1 = a0, a2 = a0, a3 = a0;
    int e = beg;
    for (; e + 3 < end; e += 4) {
        int s0 = colx[e], s1 = colx[e + 1], s2 = colx[e + 2], s3 = colx[e + 3];
        ushort4 v0 = hb4[(size_t)s0 * 32 + lane];
        ushort4 v1 = hb4[(size_t)s1 * 32 + lane];
        ushort4 v2 = hb4[(size_t)s2 * 32 + lane];
        ushort4 v3 = hb4[(size_t)s3 * 32 + lane];
        a0.x += bf2f(v0.x); a0.y += bf2f(v0.y); a0.z += bf2f(v0.z); a0.w += bf2f(v0.w);
        a1.x += bf2f(v1.x); a1.y += bf2f(v1.y); a1.z += bf2f(v1.z); a1.w += bf2f(v1.w);
        a2.x += bf2f(v2.x); a2.y += bf2f(v2.y); a2.z += bf2f(v2.z); a2.w += bf2f(v2.w);
        a3.x += bf2f(v3.x); a3.y += bf2f(v3.y); a3.z += bf2f(v3.z); a3.w += bf2f(v3.w);
    }
    for (; e < end; ++e) {
        int s = colx[e];
        ushort4 v = hb4[(size_t)s * 32 + lane];
        a0.x += bf2f(v.x); a0.y += bf2f(v.y); a0.z += bf2f(v.z); a0.w += bf2f(v.w);
    }
    float acc[4];
    acc[0] = (a0.x + a1.x) + (a2.x + a3.x);
    acc[1] = (a0.y + a1.y) + (a2.y + a3.y);
    acc[2] = (a0.z + a1.z) + (a2.z + a3.z);
    acc[3] = (a0.w + a1.w) + (a2.w + a3.w);
    int deg = end - beg;
    float inv = 1.0f / (float)(deg > 1 ? deg : 1);
    ushort4 ohi, olo;
    u16* ph = &ohi.x;
    u16* pl = &olo.x;
#pragma unroll
    for (int c = 0; c < 4; ++c) {
        float v = acc[c] * inv;
        u16 hi = f2bf(v);
        ph[c] = hi;
        pl[c] = f2bf(v - bf2f(hi));
    }
    Shi4[(size_t)g * 32 + lane] = ohi;
    Slo4[(size_t)g * 32 + lane] = olo;
}

// ---------------- MFMA GEMM, register-persistent weights ----------------
// C = act(A1@W1 + A2@W2 + bias), N = 128 cols. Wt pre-transposed [n][K] bf16 hi/lo.
// Block = 4 waves; n-group = blockIdx.x & 1 (cols 0-63 or 64-127); wave owns 16 cols.
// Each wave loads its B-fragments (hi+lo, both parts) ONCE into registers, then
// grid-strides over 32-row M macro-tiles: 16 A-loads + 48 MFMAs per tile, no LDS,
// no barriers. hi/lo split: acc += Ah*Bh + Al*Bh + Ah*Bl (fp32-equivalent).

template <int KF1, int KF2>
__global__ __launch_bounds__(256, 4) void k_gemm_mfma(
    const u16* __restrict__ A1h, const u16* __restrict__ A1l,
    const u16* __restrict__ A2h, const u16* __restrict__ A2l,
    const u16* __restrict__ B1h, const u16* __restrict__ B1l,
    const u16* __restrict__ B2h, const u16* __restrict__ B2l,
    const float* __restrict__ bias, float* __restrict__ C,
    u16* __restrict__ Hhi, u16* __restrict__ Hlo,
    int M, int do_elu)
{
    constexpr int K1 = KF1 * 32;
    constexpr int K2 = KF2 * 32;
    int lane = threadIdx.x & 63;
    int w    = threadIdx.x >> 6;
    int m16  = lane & 15;
    int quad = lane >> 4;
    int kq   = quad * 8;
    int ng   = blockIdx.x & 1;
    int ncol = (ng * 4 + w) * 16 + m16;     // this lane's output column (B row)

    // persistent B fragments
    frag_t b1h[KF1 ? KF1 : 1], b1l[KF1 ? KF1 : 1];
    frag_t b2h[KF2 ? KF2 : 1], b2l[KF2 ? KF2 : 1];
    if (KF1) {
#pragma unroll
        for (int f = 0; f < KF1; ++f) {
            b1h[f] = *(const frag_t*)&B1h[(size_t)ncol * K1 + f * 32 + kq];
            b1l[f] = *(const frag_t*)&B1l[(size_t)ncol * K1 + f * 32 + kq];
        }
    }
    if (KF2) {
#pragma unroll
        for (int f = 0; f < KF2; ++f) {
            b2h[f] = *(const frag_t*)&B2h[(size_t)ncol * K2 + f * 32 + kq];
            b2l[f] = *(const frag_t*)&B2l[(size_t)ncol * K2 + f * 32 + kq];
        }
    }

    float bv = bias[ncol];
    int nMT  = (M + 31) >> 5;
    int step = gridDim.x >> 1;

    for (int mt = blockIdx.x >> 1; mt < nMT; mt += step) {
        int r0 = mt * 32 + m16;
        int r1 = r0 + 16;
        bool v0 = r0 < M, v1 = r1 < M;
        f32x4_t acc0 = (f32x4_t){0.f, 0.f, 0.f, 0.f};
        f32x4_t acc1 = (f32x4_t){0.f, 0.f, 0.f, 0.f};

        if (KF1) {
#pragma unroll
            for (int f = 0; f < KF1; ++f) {
                frag_t x0h = {}, x0l = {}, x1h = {}, x1l = {};
                if (v0) {
                    x0h = *(const frag_t*)&A1h[(size_t)r0 * K1 + f * 32 + kq];
                    x0l = *(const frag_t*)&A1l[(size_t)r0 * K1 + f * 32 + kq];
                }
                if (v1) {
                    x1h = *(const frag_t*)&A1h[(size_t)r1 * K1 + f * 32 + kq];
                    x1l = *(const frag_t*)&A1l[(size_t)r1 * K1 + f * 32 + kq];
                }
                acc0 = __builtin_amdgcn_mfma_f32_16x16x32_bf16(x0h, b1h[f], acc0, 0, 0, 0);
                acc0 = __builtin_amdgcn_mfma_f32_16x16x32_bf16(x0l, b1h[f], acc0, 0, 0, 0);
                acc0 = __builtin_amdgcn_mfma_f32_16x16x32_bf16(x0h, b1l[f], acc0, 0, 0, 0);
                acc1 = __builtin_amdgcn_mfma_f32_16x16x32_bf16(x1h, b1h[f], acc1, 0, 0, 0);
                acc1 = __builtin_amdgcn_mfma_f32_16x16x32_bf16(x1l, b1h[f], acc1, 0, 0, 0);
                acc1 = __builtin_amdgcn_mfma_f32_16x16x32_bf16(x1h, b1l[f], acc1, 0, 0, 0);
            }
        }
        if (KF2) {
#pragma unroll
            for (int f = 0; f < KF2; ++f) {
                frag_t x0h = {}, x0l = {}, x1h = {}, x1l = {};
                if (v0) {
                    x0h = *(const frag_t*)&A2h[(size_t)r0 * K2 + f * 32 + kq];
                    x0l = *(const frag_t*)&A2l[(size_t)r0 * K2 + f * 32 + kq];
                }
                if (v1) {
                    x1h = *(const frag_t*)&A2h[(size_t)r1 * K2 + f * 32 + kq];
                    x1l = *(const frag_t*)&A2l[(size_t)r1 * K2 + f * 32 + kq];
                }
                acc0 = __builtin_amdgcn_mfma_f32_16x16x32_bf16(x0h, b2h[f], acc0, 0, 0, 0);
                acc0 = __builtin_amdgcn_mfma_f32_16x16x32_bf16(x0l, b2h[f], acc0, 0, 0, 0);
                acc0 = __builtin_amdgcn_mfma_f32_16x16x32_bf16(x0h, b2l[f], acc0, 0, 0, 0);
                acc1 = __builtin_amdgcn_mfma_f32_16x16x32_bf16(x1h, b2h[f], acc1, 0, 0, 0);
                acc1 = __builtin_amdgcn_mfma_f32_16x16x32_bf16(x1l, b2h[f], acc1, 0, 0, 0);
                acc1 = __builtin_amdgcn_mfma_f32_16x16x32_bf16(x1h, b2l[f], acc1, 0, 0, 0);
            }
        }

        // epilogue: C/D layout col = lane&15 (B side), row = quad*4 + reg (A side)
        int rb = mt * 32 + quad * 4;
#pragma unroll
        for (int r = 0; r < 4; ++r) {
            int row = rb + r;
            if (row < M) {
                float v = acc0[r] + bv;
                if (do_elu) v = (v > 0.f) ? v : expm1f(v);
                if (C) C[(size_t)row * HIDDEN + ncol] = v;
                if (Hhi) {
                    u16 hi = f2bf(v);
                    Hhi[(size_t)row * HIDDEN + ncol] = hi;
                    Hlo[(size_t)row * HIDDEN + ncol] = f2bf(v - bf2f(hi));
                }
            }
            int row2 = row + 16;
            if (row2 < M) {
                float v = acc1[r] + bv;
                if (do_elu) v = (v > 0.f) ? v : expm1f(v);
                if (C) C[(size_t)row2 * HIDDEN + ncol] = v;
                if (Hhi) {
                    u16 hi = f2bf(v);
                    Hhi[(size_t)row2 * HIDDEN + ncol] = hi;
                    Hlo[(size_t)row2 * HIDDEN + ncol] = f2bf(v - bf2f(hi));
                }
            }
        }
    }
}

// ---------------- launch ----------------

extern "C" void kernel_launch(void* const* d_in, const int* in_sizes, int n_in,
                              void* d_out, int out_size, void* d_ws, size_t ws_size,
                              hipStream_t stream) {
    const float* x        = (const float*)d_in[0];
    const int* ei         = (const int*)d_in[1];
    const float* W_in     = (const float*)d_in[2];
    const float* b_in     = (const float*)d_in[3];
    const float* W_self   = (const float*)d_in[4];
    const float* b_self   = (const float*)d_in[5];
    const float* W_nbr    = (const float*)d_in[6];
    float* out = (float*)d_out;

    const int IN_FEAT = 64;
    int N = in_sizes[0] / IN_FEAT;           // 50000
    int E = in_sizes[1] / 2;                 // 800000
    int L = in_sizes[4] / (HIDDEN * HIDDEN); // 3

    char* ws = (char*)d_ws;
    size_t off = 0;
    auto alloc = [&](size_t bytes) -> void* {
        void* p = ws + off;
        off = (off + bytes + 255) & ~(size_t)255;
        return p;
    };

    // double-buffered h (bf16 hi/lo) to avoid in-place RAW races across n-groups
    u16* hA_hi = (u16*)alloc((size_t)N * HIDDEN * 2);
    u16* hA_lo = (u16*)alloc((size_t)N * HIDDEN * 2);
    u16* hB_hi = (u16*)alloc((size_t)N * HIDDEN * 2);
    u16* hB_lo = (u16*)alloc((size_t)N * HIDDEN * 2);
    u16* xb_hi = (u16*)alloc((size_t)N * IN_FEAT * 2);
    u16* xb_lo = (u16*)alloc((size_t)N * IN_FEAT * 2);
    u16* Sb_hi = xb_hi;                                  // alias: xb dead after input GEMM
    u16* Sb_lo = (u16*)alloc((size_t)N * HIDDEN * 2);
    u16* WtI_hi = (u16*)alloc(128 * 64 * 2);
    u16* WtI_lo = (u16*)alloc(128 * 64 * 2);
    u16* WtS_hi = (u16*)alloc((size_t)L * 128 * 128 * 2);
    u16* WtS_lo = (u16*)alloc((size_t)L * 128 * 128 * 2);
    u16* WtN_hi = (u16*)alloc((size_t)L * 128 * 128 * 2);
    u16* WtN_lo = (u16*)alloc((size_t)L * 128 * 128 * 2);
    int* deg   = (int*)alloc((size_t)N * sizeof(int));
    int* rowp  = (int*)alloc((size_t)(N + 1) * sizeof(int));
    int* fillp = (int*)alloc((size_t)N * sizeof(int));
    int* colx  = (int*)alloc((size_t)E * sizeof(int));
    int* bsums = (int*)alloc(256 * sizeof(int));

    // CSR build
    hipMemsetAsync(deg, 0, (size_t)N * sizeof(int), stream);
    k_hist<<<512, 256, 0, stream>>>(ei, E, deg);
    int nb = (N + 1023) / 1024;
    k_scan1<<<nb, 1024, 0, stream>>>(deg, rowp, bsums, N);
    k_scan2<<<1, 64, 0, stream>>>(bsums, nb);
    k_scan3<<<nb, 1024, 0, stream>>>(rowp, bsums, fillp, N);
    k_fill<<<1024, 256, 0, stream>>>(ei, E, fillp, colx);

    // prep
    int wtot = 64 * 128 + 2 * L * 128 * 128;
    k_prep_w<<<(wtot + 255) / 256, 256, 0, stream>>>(W_in, W_self, W_nbr,
                                                     WtI_hi, WtI_lo, WtS_hi, WtS_lo,
                                                     WtN_hi, WtN_lo, L);
    k_prep_x<<<1024, 256, 0, stream>>>(x, xb_hi, xb_lo, N * IN_FEAT);

    const int GB = 1024;   // even: n-group = blockIdx & 1

    // input projection: hA = bf16(x @ W_in + b_in)
    k_gemm_mfma<2, 0><<<GB, 256, 0, stream>>>(
        xb_hi, xb_lo, nullptr, nullptr,
        WtI_hi, WtI_lo, nullptr, nullptr,
        b_in, nullptr, hA_hi, hA_lo, N, 0);

    u16* cur_hi = hA_hi; u16* cur_lo = hA_lo;
    u16* nxt_hi = hB_hi; u16* nxt_lo = hB_lo;

    for (int l = 0; l < L; ++l) {
        k_agg<<<(N + 7) / 8, 256, 0, stream>>>((const ushort4*)cur_hi, rowp, colx,
                                               (ushort4*)Sb_hi, (ushort4*)Sb_lo, N);
        const u16* Wsh = WtS_hi + (size_t)l * 128 * 128;
        const u16* Wsl = WtS_lo + (size_t)l * 128 * 128;
        const u16* Wnh = WtN_hi + (size_t)l * 128 * 128;
        const u16* Wnl = WtN_lo + (size_t)l * 128 * 128;
        const float* bs = b_self + (size_t)l * HIDDEN;
        bool last = (l == L - 1);
        k_gemm_mfma<4, 4><<<GB, 256, 0, stream>>>(
            cur_hi, cur_lo, Sb_hi, Sb_lo,
            Wsh, Wsl, Wnh, Wnl,
            bs, last ? out : nullptr,
            last ? nullptr : nxt_hi, last ? nullptr : nxt_lo, N, 1);
        // ping-pong
        u16* th = cur_hi; u16* tl = cur_lo;
        cur_hi = nxt_hi; cur_lo = nxt_lo;
        nxt_hi = th;     nxt_lo = tl;
    }
}

// Round 7
// 411.004 us; speedup vs baseline: 1.3443x; 1.1429x over previous
//
#include <hip/hip_runtime.h>
#include <cstdint>

#define HIDDEN 128

typedef unsigned short u16;
using frag_t  = __attribute__((ext_vector_type(8))) short;   // 8 bf16 (4 VGPRs)
using f32x4_t = __attribute__((ext_vector_type(4))) float;   // MFMA accumulator

__device__ __forceinline__ float bf2f(u16 u) {
    union { unsigned int i; float f; } c;
    c.i = ((unsigned int)u) << 16;
    return c.f;
}
__device__ __forceinline__ u16 f2bf(float f) {
    unsigned int u = __float_as_uint(f);
    unsigned int r = (u + 0x7fffu + ((u >> 16) & 1u)) >> 16;   // RNE
    return (u16)r;
}

// ---------------- CSR build (edge_index arrives as int32 from harness) ----------------

__global__ void k_hist(const int* __restrict__ ei, int E, int* __restrict__ deg) {
    int i = blockIdx.x * blockDim.x + threadIdx.x;
    int stride = gridDim.x * blockDim.x;
    for (int e = i; e < E; e += stride) atomicAdd(&deg[ei[E + e]], 1);
}

__global__ void k_scan1(const int* __restrict__ deg, int* __restrict__ rowp,
                        int* __restrict__ bsums, int n) {
    __shared__ int sh[1024];
    int t = threadIdx.x;
    int base = blockIdx.x * 1024;
    int v = (base + t < n) ? deg[base + t] : 0;
    sh[t] = v;
    __syncthreads();
    for (int off = 1; off < 1024; off <<= 1) {
        int x = sh[t];
        int y = (t >= off) ? sh[t - off] : 0;
        __syncthreads();
        sh[t] = x + y;
        __syncthreads();
    }
    if (base + t < n) rowp[base + t + 1] = sh[t];
    if (t == 1023) bsums[blockIdx.x] = sh[1023];
}

__global__ void k_scan2(int* __restrict__ bsums, int nb) {
    if (threadIdx.x == 0 && blockIdx.x == 0) {
        int run = 0;
        for (int b = 0; b < nb; ++b) { int v = bsums[b]; bsums[b] = run; run += v; }
    }
}

__global__ void k_scan3(int* __restrict__ rowp, const int* __restrict__ boffs,
                        int* __restrict__ fillp, int n) {
    int t = threadIdx.x;
    int b = blockIdx.x;
    int base = b * 1024;
    if (base + t < n) {
        int v = rowp[base + t + 1] + boffs[b];
        rowp[base + t + 1] = v;
        if (base + t + 1 < n) fillp[base + t + 1] = v;
    }
    if (b == 0 && t == 0) { rowp[0] = 0; fillp[0] = 0; }
}

__global__ void k_fill(const int* __restrict__ ei, int E,
                       int* __restrict__ fillpos, int* __restrict__ colx) {
    int i = blockIdx.x * blockDim.x + threadIdx.x;
    int stride = gridDim.x * blockDim.x;
    for (int e = i; e < E; e += stride) {
        int s = ei[e];
        int d = ei[E + e];
        int p = atomicAdd(&fillpos[d], 1);
        colx[p] = s;
    }
}

// ---------------- weight prep: transpose + split fp32 -> bf16 hi/lo, layout Wt[n][k] ----------------

__global__ void k_prep_w(const float* __restrict__ W_in,
                         const float* __restrict__ W_self,
                         const float* __restrict__ W_nbr,
                         u16* __restrict__ WtI_hi, u16* __restrict__ WtI_lo,
                         u16* __restrict__ WtS_hi, u16* __restrict__ WtS_lo,
                         u16* __restrict__ WtN_hi, u16* __restrict__ WtN_lo,
                         int L) {
    int idx = blockIdx.x * blockDim.x + threadIdx.x;
    int nIn = 64 * 128;
    int nSq = L * 128 * 128;
    float v; u16* phi; u16* plo; int o;
    if (idx < nIn) {
        int n = idx / 64, k = idx % 64;
        v = W_in[k * 128 + n]; phi = WtI_hi; plo = WtI_lo; o = n * 64 + k;
    } else if (idx < nIn + nSq) {
        int t = idx - nIn;
        int l = t / (128 * 128), r = t % (128 * 128);
        int n = r / 128, k = r % 128;
        v = W_self[l * 128 * 128 + k * 128 + n]; phi = WtS_hi; plo = WtS_lo;
        o = l * 128 * 128 + n * 128 + k;
    } else if (idx < nIn + 2 * nSq) {
        int t = idx - nIn - nSq;
        int l = t / (128 * 128), r = t % (128 * 128);
        int n = r / 128, k = r % 128;
        v = W_nbr[l * 128 * 128 + k * 128 + n]; phi = WtN_hi; plo = WtN_lo;
        o = l * 128 * 128 + n * 128 + k;
    } else return;
    u16 hi = f2bf(v);
    phi[o] = hi;
    plo[o] = f2bf(v - bf2f(hi));
}

// x [N][64] fp32 -> bf16 hi (A operands are hi-only)
__global__ void k_prep_x(const float* __restrict__ x, u16* __restrict__ xhi, int total) {
    int i = blockIdx.x * blockDim.x + threadIdx.x;
    int stride = gridDim.x * blockDim.x;
    for (; i < total; i += stride) xhi[i] = f2bf(x[i]);
}

// ---------------- aggregation: Sb_hi = bf16(mean over CSR row of hb_hi rows) ----------------

__global__ void k_agg(const ushort4* __restrict__ hb4, const int* __restrict__ rowp,
                      const int* __restrict__ colx, ushort4* __restrict__ Shi4, int n) {
    int g = (blockIdx.x * blockDim.x + threadIdx.x) >> 5;   // 32 lanes/node, lane = 4 cols
    int lane = threadIdx.x & 31;
    if (g >= n) return;
    int beg = rowp[g];
    int end = rowp[g + 1];
    float4 a0 = make_float4(0.f, 0.f, 0.f, 0.f);
    float4 a1 = a0, a2 = a0, a3 = a0;
    int e = beg;
    for (; e + 3 < end; e += 4) {
        int s0 = colx[e], s1 = colx[e + 1], s2 = colx[e + 2], s3 = colx[e + 3];
        ushort4 v0 = hb4[(size_t)s0 * 32 + lane];
        ushort4 v1 = hb4[(size_t)s1 * 32 + lane];
        ushort4 v2 = hb4[(size_t)s2 * 32 + lane];
        ushort4 v3 = hb4[(size_t)s3 * 32 + lane];
        a0.x += bf2f(v0.x); a0.y += bf2f(v0.y); a0.z += bf2f(v0.z); a0.w += bf2f(v0.w);
        a1.x += bf2f(v1.x); a1.y += bf2f(v1.y); a1.z += bf2f(v1.z); a1.w += bf2f(v1.w);
        a2.x += bf2f(v2.x); a2.y += bf2f(v2.y); a2.z += bf2f(v2.z); a2.w += bf2f(v2.w);
        a3.x += bf2f(v3.x); a3.y += bf2f(v3.y); a3.z += bf2f(v3.z); a3.w += bf2f(v3.w);
    }
    for (; e < end; ++e) {
        int s = colx[e];
        ushort4 v = hb4[(size_t)s * 32 + lane];
        a0.x += bf2f(v.x); a0.y += bf2f(v.y); a0.z += bf2f(v.z); a0.w += bf2f(v.w);
    }
    float acc[4];
    acc[0] = (a0.x + a1.x) + (a2.x + a3.x);
    acc[1] = (a0.y + a1.y) + (a2.y + a3.y);
    acc[2] = (a0.z + a1.z) + (a2.z + a3.z);
    acc[3] = (a0.w + a1.w) + (a2.w + a3.w);
    int deg = end - beg;
    float inv = 1.0f / (float)(deg > 1 ? deg : 1);
    ushort4 ohi;
    u16* ph = &ohi.x;
#pragma unroll
    for (int c = 0; c < 4; ++c) ph[c] = f2bf(acc[c] * inv);
    Shi4[(size_t)g * 32 + lane] = ohi;
}

// ---------------- MFMA GEMM, register-persistent weights, hoisted A loads ----------------
// C = act(A1@W1 + A2@W2 + bias). A bf16-hi row-major; Wt pre-transposed [n][K] bf16 hi/lo.
// n-group = blockIdx&1; wave owns 16 cols; B (hi+lo) register-persistent (loaded once).
// Per 32-row macro-tile: ALL 2*(KF1+KF2) A-fragment loads issue first (outstanding
// together), then 4*(KF1+KF2) MFMAs (Ah*Bh + Ah*Bl per acc). No LDS, no barriers.

template <int KF1, int KF2>
__global__ __launch_bounds__(256, 3) void k_gemm_mfma(
    const u16* __restrict__ A1h, const u16* __restrict__ A2h,
    const u16* __restrict__ B1h, const u16* __restrict__ B1l,
    const u16* __restrict__ B2h, const u16* __restrict__ B2l,
    const float* __restrict__ bias, float* __restrict__ C,
    u16* __restrict__ Hhi, int M, int do_elu)
{
    constexpr int K1 = KF1 * 32;
    constexpr int K2 = KF2 * 32;
    constexpr int KF = KF1 + KF2;
    int lane = threadIdx.x & 63;
    int w    = threadIdx.x >> 6;
    int m16  = lane & 15;
    int quad = lane >> 4;
    int kq   = quad * 8;
    int ng   = blockIdx.x & 1;
    int ncol = (ng * 4 + w) * 16 + m16;     // this lane's output column (B row)

    // persistent B fragments (hi+lo), loaded once
    frag_t bh[KF], bl[KF];
    if (KF1) {
#pragma unroll
        for (int f = 0; f < KF1; ++f) {
            bh[f] = *(const frag_t*)&B1h[(size_t)ncol * K1 + f * 32 + kq];
            bl[f] = *(const frag_t*)&B1l[(size_t)ncol * K1 + f * 32 + kq];
        }
    }
    if (KF2) {
#pragma unroll
        for (int f = 0; f < KF2; ++f) {
            bh[KF1 + f] = *(const frag_t*)&B2h[(size_t)ncol * K2 + f * 32 + kq];
            bl[KF1 + f] = *(const frag_t*)&B2l[(size_t)ncol * K2 + f * 32 + kq];
        }
    }

    float bv = bias[ncol];
    int nMT  = (M + 31) >> 5;
    int step = gridDim.x >> 1;

    for (int mt = blockIdx.x >> 1; mt < nMT; mt += step) {
        int r0 = mt * 32 + m16;
        int r1 = r0 + 16;
        bool v0 = r0 < M, v1 = r1 < M;

        // ---- hoisted A loads: all issue before any MFMA consumes them ----
        frag_t a0[KF], a1[KF];
        if (KF1) {
#pragma unroll
            for (int f = 0; f < KF1; ++f) {
                a0[f] = v0 ? *(const frag_t*)&A1h[(size_t)r0 * K1 + f * 32 + kq] : (frag_t){};
                a1[f] = v1 ? *(const frag_t*)&A1h[(size_t)r1 * K1 + f * 32 + kq] : (frag_t){};
            }
        }
        if (KF2) {
#pragma unroll
            for (int f = 0; f < KF2; ++f) {
                a0[KF1 + f] = v0 ? *(const frag_t*)&A2h[(size_t)r0 * K2 + f * 32 + kq] : (frag_t){};
                a1[KF1 + f] = v1 ? *(const frag_t*)&A2h[(size_t)r1 * K2 + f * 32 + kq] : (frag_t){};
            }
        }

        f32x4_t acc0 = (f32x4_t){0.f, 0.f, 0.f, 0.f};
        f32x4_t acc1 = (f32x4_t){0.f, 0.f, 0.f, 0.f};
#pragma unroll
        for (int f = 0; f < KF; ++f) {
            acc0 = __builtin_amdgcn_mfma_f32_16x16x32_bf16(a0[f], bh[f], acc0, 0, 0, 0);
            acc1 = __builtin_amdgcn_mfma_f32_16x16x32_bf16(a1[f], bh[f], acc1, 0, 0, 0);
            acc0 = __builtin_amdgcn_mfma_f32_16x16x32_bf16(a0[f], bl[f], acc0, 0, 0, 0);
            acc1 = __builtin_amdgcn_mfma_f32_16x16x32_bf16(a1[f], bl[f], acc1, 0, 0, 0);
        }

        // epilogue: C/D layout col = lane&15 (B side), row = quad*4 + reg (A side)
        int rb = mt * 32 + quad * 4;
#pragma unroll
        for (int r = 0; r < 4; ++r) {
            int row = rb + r;
            if (row < M) {
                float v = acc0[r] + bv;
                if (do_elu) v = (v > 0.f) ? v : expm1f(v);
                if (C) C[(size_t)row * HIDDEN + ncol] = v;
                if (Hhi) Hhi[(size_t)row * HIDDEN + ncol] = f2bf(v);
            }
            int row2 = row + 16;
            if (row2 < M) {
                float v = acc1[r] + bv;
                if (do_elu) v = (v > 0.f) ? v : expm1f(v);
                if (C) C[(size_t)row2 * HIDDEN + ncol] = v;
                if (Hhi) Hhi[(size_t)row2 * HIDDEN + ncol] = f2bf(v);
            }
        }
    }
}

// ---------------- launch ----------------

extern "C" void kernel_launch(void* const* d_in, const int* in_sizes, int n_in,
                              void* d_out, int out_size, void* d_ws, size_t ws_size,
                              hipStream_t stream) {
    const float* x        = (const float*)d_in[0];
    const int* ei         = (const int*)d_in[1];
    const float* W_in     = (const float*)d_in[2];
    const float* b_in     = (const float*)d_in[3];
    const float* W_self   = (const float*)d_in[4];
    const float* b_self   = (const float*)d_in[5];
    const float* W_nbr    = (const float*)d_in[6];
    float* out = (float*)d_out;

    const int IN_FEAT = 64;
    int N = in_sizes[0] / IN_FEAT;           // 50000
    int E = in_sizes[1] / 2;                 // 800000
    int L = in_sizes[4] / (HIDDEN * HIDDEN); // 3

    char* ws = (char*)d_ws;
    size_t off = 0;
    auto alloc = [&](size_t bytes) -> void* {
        void* p = ws + off;
        off = (off + bytes + 255) & ~(size_t)255;
        return p;
    };

    // double-buffered h (bf16 hi) to avoid in-place RAW races across n-groups
    u16* hA_hi = (u16*)alloc((size_t)N * HIDDEN * 2);
    u16* hB_hi = (u16*)alloc((size_t)N * HIDDEN * 2);
    u16* xb_hi = (u16*)alloc((size_t)N * IN_FEAT * 2);
    u16* Sb_hi = (u16*)alloc((size_t)N * HIDDEN * 2);
    u16* WtI_hi = (u16*)alloc(128 * 64 * 2);
    u16* WtI_lo = (u16*)alloc(128 * 64 * 2);
    u16* WtS_hi = (u16*)alloc((size_t)L * 128 * 128 * 2);
    u16* WtS_lo = (u16*)alloc((size_t)L * 128 * 128 * 2);
    u16* WtN_hi = (u16*)alloc((size_t)L * 128 * 128 * 2);
    u16* WtN_lo = (u16*)alloc((size_t)L * 128 * 128 * 2);
    int* deg   = (int*)alloc((size_t)N * sizeof(int));
    int* rowp  = (int*)alloc((size_t)(N + 1) * sizeof(int));
    int* fillp = (int*)alloc((size_t)N * sizeof(int));
    int* colx  = (int*)alloc((size_t)E * sizeof(int));
    int* bsums = (int*)alloc(256 * sizeof(int));

    // CSR build
    hipMemsetAsync(deg, 0, (size_t)N * sizeof(int), stream);
    k_hist<<<512, 256, 0, stream>>>(ei, E, deg);
    int nb = (N + 1023) / 1024;
    k_scan1<<<nb, 1024, 0, stream>>>(deg, rowp, bsums, N);
    k_scan2<<<1, 64, 0, stream>>>(bsums, nb);
    k_scan3<<<nb, 1024, 0, stream>>>(rowp, bsums, fillp, N);
    k_fill<<<1024, 256, 0, stream>>>(ei, E, fillp, colx);

    // prep
    int wtot = 64 * 128 + 2 * L * 128 * 128;
    k_prep_w<<<(wtot + 255) / 256, 256, 0, stream>>>(W_in, W_self, W_nbr,
                                                     WtI_hi, WtI_lo, WtS_hi, WtS_lo,
                                                     WtN_hi, WtN_lo, L);
    k_prep_x<<<1024, 256, 0, stream>>>(x, xb_hi, N * IN_FEAT);

    const int GB = 1024;   // even: n-group = blockIdx & 1

    // input projection: hA = bf16(x @ W_in + b_in)
    k_gemm_mfma<2, 0><<<GB, 256, 0, stream>>>(
        xb_hi, nullptr,
        WtI_hi, WtI_lo, nullptr, nullptr,
        b_in, nullptr, hA_hi, N, 0);

    u16* cur_hi = hA_hi;
    u16* nxt_hi = hB_hi;

    for (int l = 0; l < L; ++l) {
        k_agg<<<(N + 7) / 8, 256, 0, stream>>>((const ushort4*)cur_hi, rowp, colx,
                                               (ushort4*)Sb_hi, N);
        const u16* Wsh = WtS_hi + (size_t)l * 128 * 128;
        const u16* Wsl = WtS_lo + (size_t)l * 128 * 128;
        const u16* Wnh = WtN_hi + (size_t)l * 128 * 128;
        const u16* Wnl = WtN_lo + (size_t)l * 128 * 128;
        const float* bs = b_self + (size_t)l * HIDDEN;
        bool last = (l == L - 1);
        k_gemm_mfma<4, 4><<<GB, 256, 0, stream>>>(
            cur_hi, Sb_hi,
            Wsh, Wsl, Wnh, Wnl,
            bs, last ? out : nullptr,
            last ? nullptr : nxt_hi, N, 1);
        u16* t = cur_hi; cur_hi = nxt_hi; nxt_hi = t;
    }
}

// Round 8
// 388.206 us; speedup vs baseline: 1.4232x; 1.0587x over previous
//
#include <hip/hip_runtime.h>
#include <cstdint>

#define HIDDEN 128

typedef unsigned short u16;
using frag_t  = __attribute__((ext_vector_type(8))) short;   // 8 bf16 (4 VGPRs)
using f32x4_t = __attribute__((ext_vector_type(4))) float;   // MFMA accumulator

__device__ __forceinline__ float bf2f(u16 u) {
    union { unsigned int i; float f; } c;
    c.i = ((unsigned int)u) << 16;
    return c.f;
}
__device__ __forceinline__ u16 f2bf(float f) {
    unsigned int u = __float_as_uint(f);
    unsigned int r = (u + 0x7fffu + ((u >> 16) & 1u)) >> 16;   // RNE
    return (u16)r;
}

// ---------------- CSR build (edge_index arrives as int32 from harness) ----------------
// XCD-range partitioning: blocks with blockIdx&7==r own dst range [r*npr, (r+1)*npr).
// All ranges stream the full dst array (sequential, cache-absorbed); only the owning
// range writes -> each colx/deg line is dirtied by one XCD and written back once.

__global__ void k_hist(const int* __restrict__ ei, int E, int* __restrict__ deg, int npr) {
    int r  = blockIdx.x & 7;
    int lo = r * npr, hi = lo + npr;
    int nb = gridDim.x >> 3;
    int bi = blockIdx.x >> 3;
    int tid = bi * blockDim.x + threadIdx.x;
    int stride = nb * blockDim.x;
    if ((E & 3) == 0) {
        const int4* d4 = (const int4*)(ei + E);
        int nch = E >> 2;
        for (int c = tid; c < nch; c += stride) {
            int4 d = d4[c];
            if (d.x >= lo && d.x < hi) atomicAdd(&deg[d.x], 1);
            if (d.y >= lo && d.y < hi) atomicAdd(&deg[d.y], 1);
            if (d.z >= lo && d.z < hi) atomicAdd(&deg[d.z], 1);
            if (d.w >= lo && d.w < hi) atomicAdd(&deg[d.w], 1);
        }
    } else {
        for (int e = tid; e < E; e += stride) {
            int d = ei[E + e];
            if (d >= lo && d < hi) atomicAdd(&deg[d], 1);
        }
    }
}

__global__ void k_scan1(const int* __restrict__ deg, int* __restrict__ rowp,
                        int* __restrict__ bsums, int n) {
    __shared__ int sh[1024];
    int t = threadIdx.x;
    int base = blockIdx.x * 1024;
    int v = (base + t < n) ? deg[base + t] : 0;
    sh[t] = v;
    __syncthreads();
    for (int off = 1; off < 1024; off <<= 1) {
        int x = sh[t];
        int y = (t >= off) ? sh[t - off] : 0;
        __syncthreads();
        sh[t] = x + y;
        __syncthreads();
    }
    if (base + t < n) rowp[base + t + 1] = sh[t];
    if (t == 1023) bsums[blockIdx.x] = sh[1023];
}

__global__ void k_scan2(int* __restrict__ bsums, int nb) {
    if (threadIdx.x == 0 && blockIdx.x == 0) {
        int run = 0;
        for (int b = 0; b < nb; ++b) { int v = bsums[b]; bsums[b] = run; run += v; }
    }
}

__global__ void k_scan3(int* __restrict__ rowp, const int* __restrict__ boffs,
                        int* __restrict__ fillp, int n) {
    int t = threadIdx.x;
    int b = blockIdx.x;
    int base = b * 1024;
    if (base + t < n) {
        int v = rowp[base + t + 1] + boffs[b];
        rowp[base + t + 1] = v;
        if (base + t + 1 < n) fillp[base + t + 1] = v;
    }
    if (b == 0 && t == 0) { rowp[0] = 0; fillp[0] = 0; }
}

__global__ void k_fill(const int* __restrict__ ei, int E,
                       int* __restrict__ fillpos, int* __restrict__ colx, int npr) {
    int r  = blockIdx.x & 7;
    int lo = r * npr, hi = lo + npr;
    int nb = gridDim.x >> 3;
    int bi = blockIdx.x >> 3;
    int tid = bi * blockDim.x + threadIdx.x;
    int stride = nb * blockDim.x;
    if ((E & 3) == 0) {
        const int4* s4 = (const int4*)ei;
        const int4* d4 = (const int4*)(ei + E);
        int nch = E >> 2;
        for (int c = tid; c < nch; c += stride) {
            int4 d = d4[c];
            bool m0 = d.x >= lo && d.x < hi;
            bool m1 = d.y >= lo && d.y < hi;
            bool m2 = d.z >= lo && d.z < hi;
            bool m3 = d.w >= lo && d.w < hi;
            if (m0 | m1 | m2 | m3) {
                int4 s = s4[c];
                if (m0) colx[atomicAdd(&fillpos[d.x], 1)] = s.x;
                if (m1) colx[atomicAdd(&fillpos[d.y], 1)] = s.y;
                if (m2) colx[atomicAdd(&fillpos[d.z], 1)] = s.z;
                if (m3) colx[atomicAdd(&fillpos[d.w], 1)] = s.w;
            }
        }
    } else {
        for (int e = tid; e < E; e += stride) {
            int d = ei[E + e];
            if (d >= lo && d < hi) colx[atomicAdd(&fillpos[d], 1)] = ei[e];
        }
    }
}

// ---------------- weight prep: transpose + split fp32 -> bf16 hi/lo, layout Wt[n][k] ----------------

__global__ void k_prep_w(const float* __restrict__ W_in,
                         const float* __restrict__ W_self,
                         const float* __restrict__ W_nbr,
                         u16* __restrict__ WtI_hi, u16* __restrict__ WtI_lo,
                         u16* __restrict__ WtS_hi, u16* __restrict__ WtS_lo,
                         u16* __restrict__ WtN_hi, u16* __restrict__ WtN_lo,
                         int L) {
    int idx = blockIdx.x * blockDim.x + threadIdx.x;
    int nIn = 64 * 128;
    int nSq = L * 128 * 128;
    float v; u16* phi; u16* plo; int o;
    if (idx < nIn) {
        int n = idx / 64, k = idx % 64;
        v = W_in[k * 128 + n]; phi = WtI_hi; plo = WtI_lo; o = n * 64 + k;
    } else if (idx < nIn + nSq) {
        int t = idx - nIn;
        int l = t / (128 * 128), r = t % (128 * 128);
        int n = r / 128, k = r % 128;
        v = W_self[l * 128 * 128 + k * 128 + n]; phi = WtS_hi; plo = WtS_lo;
        o = l * 128 * 128 + n * 128 + k;
    } else if (idx < nIn + 2 * nSq) {
        int t = idx - nIn - nSq;
        int l = t / (128 * 128), r = t % (128 * 128);
        int n = r / 128, k = r % 128;
        v = W_nbr[l * 128 * 128 + k * 128 + n]; phi = WtN_hi; plo = WtN_lo;
        o = l * 128 * 128 + n * 128 + k;
    } else return;
    u16 hi = f2bf(v);
    phi[o] = hi;
    plo[o] = f2bf(v - bf2f(hi));
}

// x [N][64] fp32 -> bf16 hi (A operands are hi-only)
__global__ void k_prep_x(const float* __restrict__ x, u16* __restrict__ xhi, int total) {
    int i = blockIdx.x * blockDim.x + threadIdx.x;
    int stride = gridDim.x * blockDim.x;
    for (; i < total; i += stride) xhi[i] = f2bf(x[i]);
}

// ---------------- aggregation: Sb_hi = bf16(mean over CSR row of hb_hi rows) ----------------

__global__ void k_agg(const ushort4* __restrict__ hb4, const int* __restrict__ rowp,
                      const int* __restrict__ colx, ushort4* __restrict__ Shi4, int n) {
    int g = (blockIdx.x * blockDim.x + threadIdx.x) >> 5;   // 32 lanes/node, lane = 4 cols
    int lane = threadIdx.x & 31;
    if (g >= n) return;
    int beg = rowp[g];
    int end = rowp[g + 1];
    float4 a0 = make_float4(0.f, 0.f, 0.f, 0.f);
    float4 a1 = a0, a2 = a0, a3 = a0;
    int e = beg;
    for (; e + 7 < end; e += 8) {
        int s0 = colx[e],     s1 = colx[e + 1], s2 = colx[e + 2], s3 = colx[e + 3];
        int s4 = colx[e + 4], s5 = colx[e + 5], s6 = colx[e + 6], s7 = colx[e + 7];
        ushort4 v0 = hb4[(size_t)s0 * 32 + lane];
        ushort4 v1 = hb4[(size_t)s1 * 32 + lane];
        ushort4 v2 = hb4[(size_t)s2 * 32 + lane];
        ushort4 v3 = hb4[(size_t)s3 * 32 + lane];
        ushort4 v4 = hb4[(size_t)s4 * 32 + lane];
        ushort4 v5 = hb4[(size_t)s5 * 32 + lane];
        ushort4 v6 = hb4[(size_t)s6 * 32 + lane];
        ushort4 v7 = hb4[(size_t)s7 * 32 + lane];
        a0.x += bf2f(v0.x); a0.y += bf2f(v0.y); a0.z += bf2f(v0.z); a0.w += bf2f(v0.w);
        a1.x += bf2f(v1.x); a1.y += bf2f(v1.y); a1.z += bf2f(v1.z); a1.w += bf2f(v1.w);
        a2.x += bf2f(v2.x); a2.y += bf2f(v2.y); a2.z += bf2f(v2.z); a2.w += bf2f(v2.w);
        a3.x += bf2f(v3.x); a3.y += bf2f(v3.y); a3.z += bf2f(v3.z); a3.w += bf2f(v3.w);
        a0.x += bf2f(v4.x); a0.y += bf2f(v4.y); a0.z += bf2f(v4.z); a0.w += bf2f(v4.w);
        a1.x += bf2f(v5.x); a1.y += bf2f(v5.y); a1.z += bf2f(v5.z); a1.w += bf2f(v5.w);
        a2.x += bf2f(v6.x); a2.y += bf2f(v6.y); a2.z += bf2f(v6.z); a2.w += bf2f(v6.w);
        a3.x += bf2f(v7.x); a3.y += bf2f(v7.y); a3.z += bf2f(v7.z); a3.w += bf2f(v7.w);
    }
    for (; e + 3 < end; e += 4) {
        int s0 = colx[e], s1 = colx[e + 1], s2 = colx[e + 2], s3 = colx[e + 3];
        ushort4 v0 = hb4[(size_t)s0 * 32 + lane];
        ushort4 v1 = hb4[(size_t)s1 * 32 + lane];
        ushort4 v2 = hb4[(size_t)s2 * 32 + lane];
        ushort4 v3 = hb4[(size_t)s3 * 32 + lane];
        a0.x += bf2f(v0.x); a0.y += bf2f(v0.y); a0.z += bf2f(v0.z); a0.w += bf2f(v0.w);
        a1.x += bf2f(v1.x); a1.y += bf2f(v1.y); a1.z += bf2f(v1.z); a1.w += bf2f(v1.w);
        a2.x += bf2f(v2.x); a2.y += bf2f(v2.y); a2.z += bf2f(v2.z); a2.w += bf2f(v2.w);
        a3.x += bf2f(v3.x); a3.y += bf2f(v3.y); a3.z += bf2f(v3.z); a3.w += bf2f(v3.w);
    }
    for (; e < end; ++e) {
        int s = colx[e];
        ushort4 v = hb4[(size_t)s * 32 + lane];
        a0.x += bf2f(v.x); a0.y += bf2f(v.y); a0.z += bf2f(v.z); a0.w += bf2f(v.w);
    }
    float acc[4];
    acc[0] = (a0.x + a1.x) + (a2.x + a3.x);
    acc[1] = (a0.y + a1.y) + (a2.y + a3.y);
    acc[2] = (a0.z + a1.z) + (a2.z + a3.z);
    acc[3] = (a0.w + a1.w) + (a2.w + a3.w);
    int deg = end - beg;
    float inv = 1.0f / (float)(deg > 1 ? deg : 1);
    ushort4 ohi;
    u16* ph = &ohi.x;
#pragma unroll
    for (int c = 0; c < 4; ++c) ph[c] = f2bf(acc[c] * inv);
    Shi4[(size_t)g * 32 + lane] = ohi;
}

// ---------------- MFMA GEMM, register-persistent weights, hoisted A loads ----------------

template <int KF1, int KF2>
__global__ __launch_bounds__(256, 3) void k_gemm_mfma(
    const u16* __restrict__ A1h, const u16* __restrict__ A2h,
    const u16* __restrict__ B1h, const u16* __restrict__ B1l,
    const u16* __restrict__ B2h, const u16* __restrict__ B2l,
    const float* __restrict__ bias, float* __restrict__ C,
    u16* __restrict__ Hhi, int M, int do_elu)
{
    constexpr int K1 = KF1 * 32;
    constexpr int K2 = KF2 * 32;
    constexpr int KF = KF1 + KF2;
    int lane = threadIdx.x & 63;
    int w    = threadIdx.x >> 6;
    int m16  = lane & 15;
    int quad = lane >> 4;
    int kq   = quad * 8;
    int ng   = blockIdx.x & 1;
    int ncol = (ng * 4 + w) * 16 + m16;     // this lane's output column (B row)

    // persistent B fragments (hi+lo), loaded once
    frag_t bh[KF], bl[KF];
    if (KF1) {
#pragma unroll
        for (int f = 0; f < KF1; ++f) {
            bh[f] = *(const frag_t*)&B1h[(size_t)ncol * K1 + f * 32 + kq];
            bl[f] = *(const frag_t*)&B1l[(size_t)ncol * K1 + f * 32 + kq];
        }
    }
    if (KF2) {
#pragma unroll
        for (int f = 0; f < KF2; ++f) {
            bh[KF1 + f] = *(const frag_t*)&B2h[(size_t)ncol * K2 + f * 32 + kq];
            bl[KF1 + f] = *(const frag_t*)&B2l[(size_t)ncol * K2 + f * 32 + kq];
        }
    }

    float bv = bias[ncol];
    int nMT  = (M + 31) >> 5;
    int step = gridDim.x >> 1;

    for (int mt = blockIdx.x >> 1; mt < nMT; mt += step) {
        int r0 = mt * 32 + m16;
        int r1 = r0 + 16;
        bool v0 = r0 < M, v1 = r1 < M;

        // hoisted A loads: all issue before any MFMA consumes them
        frag_t a0[KF], a1[KF];
        if (KF1) {
#pragma unroll
            for (int f = 0; f < KF1; ++f) {
                a0[f] = v0 ? *(const frag_t*)&A1h[(size_t)r0 * K1 + f * 32 + kq] : (frag_t){};
                a1[f] = v1 ? *(const frag_t*)&A1h[(size_t)r1 * K1 + f * 32 + kq] : (frag_t){};
            }
        }
        if (KF2) {
#pragma unroll
            for (int f = 0; f < KF2; ++f) {
                a0[KF1 + f] = v0 ? *(const frag_t*)&A2h[(size_t)r0 * K2 + f * 32 + kq] : (frag_t){};
                a1[KF1 + f] = v1 ? *(const frag_t*)&A2h[(size_t)r1 * K2 + f * 32 + kq] : (frag_t){};
            }
        }

        f32x4_t acc0 = (f32x4_t){0.f, 0.f, 0.f, 0.f};
        f32x4_t acc1 = (f32x4_t){0.f, 0.f, 0.f, 0.f};
#pragma unroll
        for (int f = 0; f < KF; ++f) {
            acc0 = __builtin_amdgcn_mfma_f32_16x16x32_bf16(a0[f], bh[f], acc0, 0, 0, 0);
            acc1 = __builtin_amdgcn_mfma_f32_16x16x32_bf16(a1[f], bh[f], acc1, 0, 0, 0);
            acc0 = __builtin_amdgcn_mfma_f32_16x16x32_bf16(a0[f], bl[f], acc0, 0, 0, 0);
            acc1 = __builtin_amdgcn_mfma_f32_16x16x32_bf16(a1[f], bl[f], acc1, 0, 0, 0);
        }

        // epilogue: C/D layout col = lane&15 (B side), row = quad*4 + reg (A side)
        int rb = mt * 32 + quad * 4;
#pragma unroll
        for (int r = 0; r < 4; ++r) {
            int row = rb + r;
            if (row < M) {
                float v = acc0[r] + bv;
                if (do_elu) v = (v > 0.f) ? v : expm1f(v);
                if (C) C[(size_t)row * HIDDEN + ncol] = v;
                if (Hhi) Hhi[(size_t)row * HIDDEN + ncol] = f2bf(v);
            }
            int row2 = row + 16;
            if (row2 < M) {
                float v = acc1[r] + bv;
                if (do_elu) v = (v > 0.f) ? v : expm1f(v);
                if (C) C[(size_t)row2 * HIDDEN + ncol] = v;
                if (Hhi) Hhi[(size_t)row2 * HIDDEN + ncol] = f2bf(v);
            }
        }
    }
}

// ---------------- launch ----------------

extern "C" void kernel_launch(void* const* d_in, const int* in_sizes, int n_in,
                              void* d_out, int out_size, void* d_ws, size_t ws_size,
                              hipStream_t stream) {
    const float* x        = (const float*)d_in[0];
    const int* ei         = (const int*)d_in[1];
    const float* W_in     = (const float*)d_in[2];
    const float* b_in     = (const float*)d_in[3];
    const float* W_self   = (const float*)d_in[4];
    const float* b_self   = (const float*)d_in[5];
    const float* W_nbr    = (const float*)d_in[6];
    float* out = (float*)d_out;

    const int IN_FEAT = 64;
    int N = in_sizes[0] / IN_FEAT;           // 50000
    int E = in_sizes[1] / 2;                 // 800000
    int L = in_sizes[4] / (HIDDEN * HIDDEN); // 3

    char* ws = (char*)d_ws;
    size_t off = 0;
    auto alloc = [&](size_t bytes) -> void* {
        void* p = ws + off;
        off = (off + bytes + 255) & ~(size_t)255;
        return p;
    };

    u16* hA_hi = (u16*)alloc((size_t)N * HIDDEN * 2);
    u16* hB_hi = (u16*)alloc((size_t)N * HIDDEN * 2);
    u16* xb_hi = (u16*)alloc((size_t)N * IN_FEAT * 2);
    u16* Sb_hi = (u16*)alloc((size_t)N * HIDDEN * 2);
    u16* WtI_hi = (u16*)alloc(128 * 64 * 2);
    u16* WtI_lo = (u16*)alloc(128 * 64 * 2);
    u16* WtS_hi = (u16*)alloc((size_t)L * 128 * 128 * 2);
    u16* WtS_lo = (u16*)alloc((size_t)L * 128 * 128 * 2);
    u16* WtN_hi = (u16*)alloc((size_t)L * 128 * 128 * 2);
    u16* WtN_lo = (u16*)alloc((size_t)L * 128 * 128 * 2);
    int* deg   = (int*)alloc((size_t)N * sizeof(int));
    int* rowp  = (int*)alloc((size_t)(N + 1) * sizeof(int));
    int* fillp = (int*)alloc((size_t)N * sizeof(int));
    int* colx  = (int*)alloc((size_t)E * sizeof(int));
    int* bsums = (int*)alloc(256 * sizeof(int));

    int npr = (N + 7) / 8;   // nodes per XCD range

    // CSR build (XCD-range-partitioned scatters)
    hipMemsetAsync(deg, 0, (size_t)N * sizeof(int), stream);
    k_hist<<<2048, 256, 0, stream>>>(ei, E, deg, npr);
    int nb = (N + 1023) / 1024;
    k_scan1<<<nb, 1024, 0, stream>>>(deg, rowp, bsums, N);
    k_scan2<<<1, 64, 0, stream>>>(bsums, nb);
    k_scan3<<<nb, 1024, 0, stream>>>(rowp, bsums, fillp, N);
    k_fill<<<2048, 256, 0, stream>>>(ei, E, fillp, colx, npr);

    // prep
    int wtot = 64 * 128 + 2 * L * 128 * 128;
    k_prep_w<<<(wtot + 255) / 256, 256, 0, stream>>>(W_in, W_self, W_nbr,
                                                     WtI_hi, WtI_lo, WtS_hi, WtS_lo,
                                                     WtN_hi, WtN_lo, L);
    k_prep_x<<<1024, 256, 0, stream>>>(x, xb_hi, N * IN_FEAT);

    const int GB = 1024;   // even: n-group = blockIdx & 1

    // input projection: hA = bf16(x @ W_in + b_in)
    k_gemm_mfma<2, 0><<<GB, 256, 0, stream>>>(
        xb_hi, nullptr,
        WtI_hi, WtI_lo, nullptr, nullptr,
        b_in, nullptr, hA_hi, N, 0);

    u16* cur_hi = hA_hi;
    u16* nxt_hi = hB_hi;

    for (int l = 0; l < L; ++l) {
        k_agg<<<(N + 7) / 8, 256, 0, stream>>>((const ushort4*)cur_hi, rowp, colx,
                                               (ushort4*)Sb_hi, N);
        const u16* Wsh = WtS_hi + (size_t)l * 128 * 128;
        const u16* Wsl = WtS_lo + (size_t)l * 128 * 128;
        const u16* Wnh = WtN_hi + (size_t)l * 128 * 128;
        const u16* Wnl = WtN_lo + (size_t)l * 128 * 128;
        const float* bs = b_self + (size_t)l * HIDDEN;
        bool last = (l == L - 1);
        k_gemm_mfma<4, 4><<<GB, 256, 0, stream>>>(
            cur_hi, Sb_hi,
            Wsh, Wsl, Wnh, Wnl,
            bs, last ? out : nullptr,
            last ? nullptr : nxt_hi, N, 1);
        u16* t = cur_hi; cur_hi = nxt_hi; nxt_hi = t;
    }
}